// Round 4
// baseline (612.496 us; speedup 1.0000x reference)
//
#include <hip/hip_runtime.h>
#include <hip/hip_bf16.h>

// RNN: B=1024, T=512, E=64, H=128, OUT=2, VOCAB=4411
// R4: MFMA recurrence. Per step: z^T[j][b] = sum_k W_hh[j][k] h[b][k]
//   - Block = 16 batch rows, 128 threads = 2 waves; wave w owns j in [64w,64w+64).
//   - A-operand = W_hh bf16 fragments: STATIC, 16 frags x 4 VGPR = 64 VGPR/lane.
//     (Fixes R1-R3's fatal flaw: VALU formulation needed 128 live regs/thread;
//      MFMA distributes the weight tile across the wave.)
//   - B-operand = h (bf16) in double-buffered LDS, XOR-swizzled 16B blocks
//     (4 ds_read_b128 per wave-step, conflict-minimized).
//   - C init = x_proj gather from precomputed fp32 pe[v][j] table (kernel 1),
//     tokens + pe rows software-pipelined 1-2 steps ahead from global (L1/L2-hot).
//   - 1 barrier/step. tanh in fp32 via __expf.
// MFMA layouts (gfx950, m89/m91-verified):
//   A[m][k]: lane = m + 16*(k>>3) (per 32-K tile: m=L&15, k=(L>>4)*8+s)
//   B[k][n]: n=L&15, k=(L>>4)*8+s
//   D[m][n]: n=L&15, m=(L>>4)*4+reg

constexpr int Bc    = 1024;
constexpr int Tc    = 512;
constexpr int Ec    = 64;
constexpr int Hc    = 128;
constexpr int OUTc  = 2;
constexpr int VOCAB = 4411;

typedef short  short8  __attribute__((ext_vector_type(8)));
typedef float  floatx4 __attribute__((ext_vector_type(4)));

__device__ __forceinline__ unsigned short f2bf(float x) {
    union { __hip_bfloat16 h; unsigned short u; } v;
    v.h = __float2bfloat16(x);
    return v.u;
}
__device__ __forceinline__ float bf2f(unsigned short u) {
    union { float f; unsigned int u; } c;
    c.u = ((unsigned int)u) << 16;
    return c.f;
}
__device__ __forceinline__ float fast_tanh(float z) {
    const float e = __expf(2.0f * z);      // inf-safe: z>>0 -> 1, z<<0 -> -1
    return 1.0f - 2.0f / (e + 1.0f);
}

// ---------------- Kernel 1: pe[v][j] = emb[v].W_ih[j] + b_ih[j] + b_hh[j] ----
__global__ __launch_bounds__(Hc) void pe_kernel(
    const float* __restrict__ emb, const float* __restrict__ W_ih,
    const float* __restrict__ b_ih, const float* __restrict__ b_hh,
    float* __restrict__ pe)
{
    const int v = blockIdx.x;
    const int j = threadIdx.x;
    const float* er = emb + v * Ec;
    const float* wr = W_ih + j * Ec;
    float a0 = b_ih[j] + b_hh[j], a1 = 0.f, a2 = 0.f, a3 = 0.f;
#pragma unroll
    for (int e = 0; e < Ec; e += 4) {
        const float4 E = *(const float4*)(er + e);
        const float4 W = *(const float4*)(wr + e);
        a0 = fmaf(E.x, W.x, a0);
        a1 = fmaf(E.y, W.y, a1);
        a2 = fmaf(E.z, W.z, a2);
        a3 = fmaf(E.w, W.w, a3);
    }
    pe[v * Hc + j] = (a0 + a1) + (a2 + a3);
}

// ---------------- Kernel 2: MFMA recurrence ----------------
// LDS h buffer: HT[buf][b][k] bf16, row stride 136 ushorts (272 B), 16B blocks
// XOR-swizzled by (b&7):  off(b,k) = b*136 + ((k>>3) ^ (b&7))*8 + (k&7)
constexpr int HT_STRIDE = 136;            // ushorts per b-row (128 + 8 pad)
constexpr int HT_BUF    = 16 * HT_STRIDE; // ushorts per buffer

__global__ __launch_bounds__(128, 2) void rnn_mfma(
    const int*   __restrict__ inputs,  // [B, T]
    const float* __restrict__ pe,      // [VOCAB, H]
    const float* __restrict__ W_hh,    // [H, H]
    const float* __restrict__ W_lin,   // [OUT, H]
    const float* __restrict__ b_lin,   // [OUT]
    float* __restrict__ out)           // [B, OUT]
{
    const int tid = threadIdx.x;
    const int w   = tid >> 6;      // wave 0/1 -> j half
    const int L   = tid & 63;
    const int q   = L >> 4;        // 0..3
    const int b   = L & 15;        // batch sub-row (and A-row / B-col lane field)
    const int blk = blockIdx.x;
    const int row = blk * 16 + b;  // global batch row for this lane
    const int jb  = w * 64;

    __shared__ __align__(16) unsigned short HT[2 * HT_BUF];

    // Zero both h buffers (h_0 = 0).
    {
        unsigned int* z = (unsigned int*)HT;
        for (int i = tid; i < HT_BUF; i += 128) z[i] = 0u;  // 2*HT_BUF ushorts
    }

    // ---- Static A fragments: W_hh rows [jb, jb+64), bf16. 64 VGPRs. ----
    short8 wfrag[4][4];  // [jt][kt]
#pragma unroll
    for (int jt = 0; jt < 4; ++jt) {
        const float* wr = W_hh + (jb + jt * 16 + b) * Hc;  // A row m = L&15
#pragma unroll
        for (int kt = 0; kt < 4; ++kt) {
            const float4 w0 = *(const float4*)(wr + kt * 32 + q * 8);
            const float4 w1 = *(const float4*)(wr + kt * 32 + q * 8 + 4);
            union { short8 s; unsigned short u[8]; } uf;
            uf.u[0] = f2bf(w0.x); uf.u[1] = f2bf(w0.y);
            uf.u[2] = f2bf(w0.z); uf.u[3] = f2bf(w0.w);
            uf.u[4] = f2bf(w1.x); uf.u[5] = f2bf(w1.y);
            uf.u[6] = f2bf(w1.z); uf.u[7] = f2bf(w1.w);
            wfrag[jt][kt] = uf.s;
        }
    }
#pragma unroll
    for (int jt = 0; jt < 4; ++jt)
        asm volatile("" : "+v"(wfrag[jt][0]), "+v"(wfrag[jt][1]),
                          "+v"(wfrag[jt][2]), "+v"(wfrag[jt][3]));

    // Precomputed LDS addresses (loop-invariant).
    unsigned short* const ht0 = HT;
    unsigned short* const ht1 = HT + HT_BUF;
    int rd_off[4], wr_off[4];
#pragma unroll
    for (int kt = 0; kt < 4; ++kt)                     // B-read: k-group = kt*4+q
        rd_off[kt] = b * HT_STRIDE + (((kt * 4 + q) ^ (b & 7)) * 8);
#pragma unroll
    for (int jt = 0; jt < 4; ++jt) {                   // h-write: j = jb+jt*16+q*4
        const int j0 = jb + jt * 16 + q * 4;
        wr_off[jt] = b * HT_STRIDE + (((j0 >> 3) ^ (b & 7)) * 8) + (j0 & 7);
    }

    // ---- Software pipeline: tokens 2 ahead, xp (pe rows) 1 ahead. ----
    const int* trow = inputs + row * Tc;
    int tk1 = trow[0];
    float4 xpc[4];
#pragma unroll
    for (int jt = 0; jt < 4; ++jt)
        xpc[jt] = *(const float4*)(pe + (long)tk1 * Hc + jb + jt * 16 + q * 4);
    tk1 = trow[1 < Tc ? 1 : 0];

    __syncthreads();

    for (int t = 0; t < Tc; ++t) {
        const int buf = t & 1;
        unsigned short* const rbuf = buf ? ht1 : ht0;
        unsigned short* const wbuf = buf ? ht0 : ht1;

        // Prefetch: token t+2, pe row for t+1.
        const int tk2 = trow[(t + 2 < Tc) ? (t + 2) : (Tc - 1)];
        float4 xpn[4];
#pragma unroll
        for (int jt = 0; jt < 4; ++jt)
            xpn[jt] = *(const float4*)(pe + (long)tk1 * Hc + jb + jt * 16 + q * 4);

        // B fragments: h[b][k] bf16 from LDS.
        short8 bfrag[4];
#pragma unroll
        for (int kt = 0; kt < 4; ++kt)
            bfrag[kt] = *(const short8*)(rbuf + rd_off[kt]);

        // 16 MFMAs: acc[jt] = xp + sum_kt W-tile x h-tile.
        floatx4 acc[4];
#pragma unroll
        for (int jt = 0; jt < 4; ++jt) {
            acc[jt] = (floatx4){xpc[jt].x, xpc[jt].y, xpc[jt].z, xpc[jt].w};
#pragma unroll
            for (int kt = 0; kt < 4; ++kt)
                acc[jt] = __builtin_amdgcn_mfma_f32_16x16x32_bf16(
                    wfrag[jt][kt], bfrag[kt], acc[jt], 0, 0, 0);
        }

        // tanh -> bf16 pairs -> swizzled LDS write (4 b32 writes per jt-pair).
#pragma unroll
        for (int jt = 0; jt < 4; ++jt) {
            const float h0 = fast_tanh(acc[jt][0]);
            const float h1 = fast_tanh(acc[jt][1]);
            const float h2 = fast_tanh(acc[jt][2]);
            const float h3 = fast_tanh(acc[jt][3]);
            const unsigned int p0 = ((unsigned int)f2bf(h1) << 16) | f2bf(h0);
            const unsigned int p1 = ((unsigned int)f2bf(h3) << 16) | f2bf(h2);
            *(unsigned int*)(wbuf + wr_off[jt])     = p0;
            *(unsigned int*)(wbuf + wr_off[jt] + 2) = p1;
        }

        __syncthreads();
        xpc[0] = xpn[0]; xpc[1] = xpn[1]; xpc[2] = xpn[2]; xpc[3] = xpn[3];
        tk1 = tk2;
    }

    // Final h is in buffer 0 (t=511 wrote buf^1 = 0). Linear head.
    if (tid < 16 * OUTc) {
        const int bb = tid >> 1, o = tid & 1;
        float s = b_lin[o];
        const float* wl = W_lin + o * Hc;
#pragma unroll 8
        for (int k = 0; k < Hc; ++k) {
            const unsigned short hu =
                ht0[bb * HT_STRIDE + (((k >> 3) ^ (bb & 7)) * 8) + (k & 7)];
            s = fmaf(bf2f(hu), wl[k], s);
        }
        out[(blk * 16 + bb) * OUTc + o] = s;
    }
}

extern "C" void kernel_launch(void* const* d_in, const int* in_sizes, int n_in,
                              void* d_out, int out_size, void* d_ws, size_t ws_size,
                              hipStream_t stream) {
    const int*   inputs    = (const int*)d_in[0];
    const float* emb_table = (const float*)d_in[1];
    const float* W_ih      = (const float*)d_in[2];
    const float* W_hh      = (const float*)d_in[3];
    const float* b_ih      = (const float*)d_in[4];
    const float* b_hh      = (const float*)d_in[5];
    const float* W_lin     = (const float*)d_in[6];
    const float* b_lin     = (const float*)d_in[7];
    float* out = (float*)d_out;

    float* pe = (float*)d_ws;  // VOCAB*H*4 = 2.26 MB (ws verified >= this in R3)
    pe_kernel<<<VOCAB, Hc, 0, stream>>>(emb_table, W_ih, b_ih, b_hh, pe);
    rnn_mfma<<<Bc / 16, 128, 0, stream>>>(inputs, pe, W_hh, W_lin, b_lin, out);
}

// Round 5
// 282.042 us; speedup vs baseline: 2.1717x; 2.1717x over previous
//
#include <hip/hip_runtime.h>
#include <hip/hip_bf16.h>

// RNN: B=1024, T=512, E=64, H=128, OUT=2, VOCAB=4411
// R5 (from R4's 531us latency post-mortem; wall time = 512 x per-step chain):
//  1. Barrier WITHOUT vmcnt drain: asm "s_waitcnt lgkmcnt(0); s_barrier".
//     __syncthreads() drains vmcnt(0) -> every step waited on the pe global
//     prefetch (m97 lesson). Now pe loads stay in flight across steps.
//  2. Division-free tanh: 1 - 2*rcp(exp2(k*z)+1). The IEEE div sequence
//     (div_scale/fmas/fixup, ~10 ops x16 values) is gone.
//  3. 4 waves/block (wave w owns j in [32w,32w+32)): halves per-wave tanh
//     and MFMA issue on the critical path vs R4's 2 waves.
//  4. Plain stride-136-ushort h layout (no XOR): b128 reads conflict-free
//     (8 consecutive lanes -> 8 distinct 16B banks), b64 writes 2-way max
//     (free per m136). Tokens staged in LDS (pad 513) -> no in-loop global
//     token reads.
// MFMA 16x16x32_bf16 layouts (m89/m91): A[m][k]: m=L&15, k=(L>>4)*8+s;
// B[k][n]: n=L&15, k=(L>>4)*8+s; D[m][n]: n=L&15, m=(L>>4)*4+reg.

constexpr int Bc    = 1024;
constexpr int Tc    = 512;
constexpr int Ec    = 64;
constexpr int Hc    = 128;
constexpr int OUTc  = 2;
constexpr int VOCAB = 4411;

typedef short  short8  __attribute__((ext_vector_type(8)));
typedef float  floatx4 __attribute__((ext_vector_type(4)));

__device__ __forceinline__ unsigned short f2bf(float x) {
    union { __hip_bfloat16 h; unsigned short u; } v;
    v.h = __float2bfloat16(x);
    return v.u;
}
__device__ __forceinline__ float bf2f(unsigned short u) {
    union { float f; unsigned int u; } c;
    c.u = ((unsigned int)u) << 16;
    return c.f;
}
// tanh(z) = 1 - 2/(e^{2z}+1), division-free: v_exp_f32 + v_rcp_f32.
// Saturation exact: z>>0 -> rcp(inf)=0 -> 1; z<<0 -> rcp(1)=1 -> -1.
__device__ __forceinline__ float fast_tanh(float z) {
    const float e = __builtin_amdgcn_exp2f(2.8853900817779268f * z);
    return 1.0f - 2.0f * __builtin_amdgcn_rcpf(e + 1.0f);
}

// Workgroup barrier that drains ONLY lgkmcnt (LDS), not vmcnt (global).
#define LGKM_BARRIER() asm volatile("s_waitcnt lgkmcnt(0)\n\ts_barrier" ::: "memory")

// ---------------- Kernel 1: pe[v][j] = emb[v].W_ih[j] + b_ih[j] + b_hh[j] ----
// 32 vocab rows per block; emb rows staged in LDS; W_ih row j in registers.
constexpr int PV = 32;
__global__ __launch_bounds__(Hc) void pe_kernel(
    const float* __restrict__ emb, const float* __restrict__ W_ih,
    const float* __restrict__ b_ih, const float* __restrict__ b_hh,
    float* __restrict__ pe)
{
    const int j  = threadIdx.x;
    const int v0 = blockIdx.x * PV;

    __shared__ float es[PV * Ec];   // 8 KB
    for (int i = j; i < PV * Ec / 4; i += Hc) {
        const int flat = i * 4, vv = flat >> 6;
        if (v0 + vv < VOCAB)
            *(float4*)&es[flat] = *(const float4*)(emb + (long)(v0 + vv) * Ec + (flat & 63));
    }

    float4 wr[Ec / 4];
#pragma unroll
    for (int e = 0; e < Ec / 4; ++e)
        wr[e] = *(const float4*)(W_ih + j * Ec + e * 4);
#pragma unroll
    for (int e = 0; e < Ec / 4; ++e)
        asm volatile("" : "+v"(wr[e].x), "+v"(wr[e].y), "+v"(wr[e].z), "+v"(wr[e].w));
    const float bias = b_ih[j] + b_hh[j];

    __syncthreads();

    for (int vv = 0; vv < PV; ++vv) {
        if (v0 + vv >= VOCAB) break;
        const float* er = &es[vv * Ec];
        float a0 = bias, a1 = 0.f, a2 = 0.f, a3 = 0.f;
#pragma unroll
        for (int e = 0; e < Ec / 4; ++e) {
            const float4 E = *(const float4*)(er + 4 * e);  // LDS broadcast
            a0 = fmaf(E.x, wr[e].x, a0);
            a1 = fmaf(E.y, wr[e].y, a1);
            a2 = fmaf(E.z, wr[e].z, a2);
            a3 = fmaf(E.w, wr[e].w, a3);
        }
        pe[(long)(v0 + vv) * Hc + j] = (a0 + a1) + (a2 + a3);
    }
}

// ---------------- Kernel 2: MFMA recurrence ----------------
constexpr int HT_STRIDE  = 136;            // ushorts per b-row (128 + 8 pad)
constexpr int HT_BUF     = 16 * HT_STRIDE; // ushorts per buffer
constexpr int TOK_STRIDE = 513;            // ints per b-row (512 + 1 pad)

__global__ __attribute__((amdgpu_flat_work_group_size(256, 256)))
void rnn_mfma(
    const int*   __restrict__ inputs,  // [B, T]
    const float* __restrict__ pe,      // [VOCAB, H]
    const float* __restrict__ W_hh,    // [H, H]
    const float* __restrict__ W_lin,   // [OUT, H]
    const float* __restrict__ b_lin,   // [OUT]
    float* __restrict__ out)           // [B, OUT]
{
    const int tid = threadIdx.x;
    const int w   = tid >> 6;      // wave 0..3 -> j in [32w, 32w+32)
    const int L   = tid & 63;
    const int q   = L >> 4;        // 0..3
    const int b   = L & 15;        // batch sub-row / MFMA lane col
    const int blk = blockIdx.x;
    const int jb  = w * 32;

    __shared__ __align__(16) unsigned short HT[2 * HT_BUF];
    __shared__ int toks[16 * TOK_STRIDE];

    // Stage this block's 16 token rows (16x512 ints) into LDS, coalesced.
    {
        const int base = blk * 16 * Tc;
        for (int i = tid; i < 16 * Tc / 4; i += 256) {
            const int4 v4 = *(const int4*)(inputs + base + i * 4);
            const int bb = (i * 4) >> 9, t0 = (i * 4) & 511;
            int* dst = &toks[bb * TOK_STRIDE + t0];
            dst[0] = v4.x; dst[1] = v4.y; dst[2] = v4.z; dst[3] = v4.w;
        }
    }
    // Zero h buffer 0 (h_0 = 0).
    {
        unsigned int* z = (unsigned int*)HT;
        for (int i = tid; i < HT_BUF / 2; i += 256) z[i] = 0u;
    }

    // Static A fragments: W_hh rows [jb, jb+32) as bf16. 2x4 frags = 32 VGPR.
    short8 wfrag[2][4];
#pragma unroll
    for (int jt = 0; jt < 2; ++jt) {
        const float* wr = W_hh + (jb + jt * 16 + b) * Hc;   // A row m = L&15
#pragma unroll
        for (int kt = 0; kt < 4; ++kt) {
            const float4 w0 = *(const float4*)(wr + kt * 32 + q * 8);
            const float4 w1 = *(const float4*)(wr + kt * 32 + q * 8 + 4);
            union { short8 s; unsigned short u[8]; } uf;
            uf.u[0] = f2bf(w0.x); uf.u[1] = f2bf(w0.y);
            uf.u[2] = f2bf(w0.z); uf.u[3] = f2bf(w0.w);
            uf.u[4] = f2bf(w1.x); uf.u[5] = f2bf(w1.y);
            uf.u[6] = f2bf(w1.z); uf.u[7] = f2bf(w1.w);
            wfrag[jt][kt] = uf.s;
        }
    }
#pragma unroll
    for (int jt = 0; jt < 2; ++jt)
        asm volatile("" : "+v"(wfrag[jt][0]), "+v"(wfrag[jt][1]),
                          "+v"(wfrag[jt][2]), "+v"(wfrag[jt][3]));

    unsigned short* const ht0 = HT;
    unsigned short* const ht1 = HT + HT_BUF;
    int rd_off[4], wr_off[2];
#pragma unroll
    for (int kt = 0; kt < 4; ++kt)
        rd_off[kt] = b * HT_STRIDE + (kt * 4 + q) * 8;      // k = kt*32+q*8
#pragma unroll
    for (int jt = 0; jt < 2; ++jt)
        wr_off[jt] = b * HT_STRIDE + (jb + jt * 16 + q * 4); // j0 = jb+jt*16+q*4

    const int* tr = &toks[b * TOK_STRIDE];

    __syncthreads();   // tokens + zeroed h0 visible (one-time full drain, fine)

    // Prologue: xp for t=0 and t=1.
    float4 xpc[2], xpn[2];
    {
        const int t0 = tr[0], t1 = tr[1];
#pragma unroll
        for (int jt = 0; jt < 2; ++jt) {
            xpc[jt] = *(const float4*)(pe + (long)t0 * Hc + jb + jt * 16 + q * 4);
            xpn[jt] = *(const float4*)(pe + (long)t1 * Hc + jb + jt * 16 + q * 4);
        }
    }

    for (int t = 0; t < Tc; ++t) {
        unsigned short* const rbuf = (t & 1) ? ht1 : ht0;
        unsigned short* const wbuf = (t & 1) ? ht0 : ht1;

        // B fragments: h[b][k] bf16 (conflict-free b128 reads).
        short8 bfrag[4];
#pragma unroll
        for (int kt = 0; kt < 4; ++kt)
            bfrag[kt] = *(const short8*)(rbuf + rd_off[kt]);

        // Prefetch pe row for t+2 (stays in flight across the lgkm barrier).
        float4 xp2[2];
        {
            const int tk = tr[(t + 2 < Tc) ? (t + 2) : (Tc - 1)];
#pragma unroll
            for (int jt = 0; jt < 2; ++jt)
                xp2[jt] = *(const float4*)(pe + (long)tk * Hc + jb + jt * 16 + q * 4);
        }

        // 8 MFMAs: acc[jt] = xp + sum_kt Wtile x htile.
        floatx4 acc[2];
#pragma unroll
        for (int jt = 0; jt < 2; ++jt) {
            acc[jt] = (floatx4){xpc[jt].x, xpc[jt].y, xpc[jt].z, xpc[jt].w};
#pragma unroll
            for (int kt = 0; kt < 4; ++kt)
                acc[jt] = __builtin_amdgcn_mfma_f32_16x16x32_bf16(
                    wfrag[jt][kt], bfrag[kt], acc[jt], 0, 0, 0);
        }

        // tanh -> bf16 -> one b64 LDS write per jt (2-way max = free).
#pragma unroll
        for (int jt = 0; jt < 2; ++jt) {
            const float h0 = fast_tanh(acc[jt][0]);
            const float h1 = fast_tanh(acc[jt][1]);
            const float h2 = fast_tanh(acc[jt][2]);
            const float h3 = fast_tanh(acc[jt][3]);
            uint2 pk;
            pk.x = ((unsigned int)f2bf(h1) << 16) | f2bf(h0);
            pk.y = ((unsigned int)f2bf(h3) << 16) | f2bf(h2);
            *(uint2*)(wbuf + wr_off[jt]) = pk;
        }

        LGKM_BARRIER();   // drains LDS only; pe prefetch stays outstanding

        xpc[0] = xpn[0]; xpc[1] = xpn[1];
        xpn[0] = xp2[0]; xpn[1] = xp2[1];
    }

    // Final h is in ht0 (t=511 wrote ht0). Linear head.
    if (tid < 16 * OUTc) {
        const int bb = tid >> 1, o = tid & 1;
        float s = b_lin[o];
        const float* wl = W_lin + o * Hc;
#pragma unroll 8
        for (int k = 0; k < Hc; ++k)
            s = fmaf(bf2f(ht0[bb * HT_STRIDE + k]), wl[k], s);
        out[(blk * 16 + bb) * OUTc + o] = s;
    }
}

extern "C" void kernel_launch(void* const* d_in, const int* in_sizes, int n_in,
                              void* d_out, int out_size, void* d_ws, size_t ws_size,
                              hipStream_t stream) {
    const int*   inputs    = (const int*)d_in[0];
    const float* emb_table = (const float*)d_in[1];
    const float* W_ih      = (const float*)d_in[2];
    const float* W_hh      = (const float*)d_in[3];
    const float* b_ih      = (const float*)d_in[4];
    const float* b_hh      = (const float*)d_in[5];
    const float* W_lin     = (const float*)d_in[6];
    const float* b_lin     = (const float*)d_in[7];
    float* out = (float*)d_out;

    float* pe = (float*)d_ws;  // VOCAB*H*4 = 2.26 MB
    pe_kernel<<<(VOCAB + PV - 1) / PV, Hc, 0, stream>>>(emb_table, W_ih, b_ih, b_hh, pe);
    rnn_mfma<<<Bc / 16, 256, 0, stream>>>(inputs, pe, W_hh, W_lin, b_lin, out);
}